// Round 11
// baseline (571.131 us; speedup 1.0000x reference)
//
#include <hip/hip_runtime.h>
#include <hip/hip_bf16.h>
#include <cstddef>

#define NN 50000
#define EE 800000

typedef __attribute__((ext_vector_type(8))) short short8;
typedef __attribute__((ext_vector_type(4))) float f32x4;

#define GLB __attribute__((address_space(1)))
#define LDS __attribute__((address_space(3)))

__device__ __forceinline__ float leaky(float x) { return x >= 0.f ? x : 0.2f * x; }
__device__ __forceinline__ float bf2f(unsigned short u) {
  return __uint_as_float(((unsigned int)u) << 16);
}
__device__ __forceinline__ float bflo(unsigned int v) { return __uint_as_float(v << 16); }
__device__ __forceinline__ float bfhi(unsigned int v) { return __uint_as_float(v & 0xFFFF0000u); }
__device__ __forceinline__ unsigned short f2bf(float f) {
  __hip_bfloat16 b = __float2bfloat16(f);
  return __builtin_bit_cast(unsigned short, b);
}
__device__ __forceinline__ void accum8(float a, uint4 v, float* acc) {
  acc[0] += a * bflo(v.x); acc[1] += a * bfhi(v.x);
  acc[2] += a * bflo(v.y); acc[3] += a * bfhi(v.y);
  acc[4] += a * bflo(v.z); acc[5] += a * bfhi(v.z);
  acc[6] += a * bflo(v.w); acc[7] += a * bfhi(v.w);
}

// ==== bf16 MFMA GEMM, BM=64/BN=128, VOLLEY-staged (round-17) ================
template <int LAYER>
__global__ __launch_bounds__(256) void gemm128_k(const unsigned short* __restrict__ A,
                                                 const unsigned short* __restrict__ Bt,
                                                 unsigned short* __restrict__ Cb,
                                                 int K,
                                                 const float* __restrict__ a_s,
                                                 const float* __restrict__ a_d,
                                                 float* __restrict__ als,
                                                 float* __restrict__ ald,
                                                 float* __restrict__ selfex) {
  __shared__ __align__(16) unsigned short As[4][64 * 32];    // 16 KB
  __shared__ __align__(16) unsigned short Bs[4][128 * 32];   // 32 KB
  const int tid = threadIdx.x;
  const int lane = tid & 63;
  const int w = tid >> 6;
  const int bm = blockIdx.x * 64;
  const int bn = blockIdx.y * 128;
  const int quad = lane >> 4;
  const int l16 = lane & 15;
  const int lrow = lane >> 2;   // 0..15 within a staging call
  const int lseg = lane & 3;
  f32x4 acc[8] = {};

  for (int kv = 0; kv < K; kv += 128) {
    if (kv) __syncthreads();  // protect LDS reuse after previous compute
#pragma unroll
    for (int ks = 0; ks < 4; ++ks) {
      const int kc = kv + ks * 32;
      {  // A tile: 1 call/wave/kstep (16 rows, row = 64B = 4 lanes x 16B)
        int row = w * 16 + lrow;
        int g = lseg ^ ((row >> 2) & 3);
        int sr = bm + row; if (sr >= NN) sr = NN - 1;
        const unsigned short* gp = A + (size_t)sr * K + kc + g * 8;
        __builtin_amdgcn_global_load_lds((const GLB void*)gp,
                                         (LDS void*)&As[ks][(w * 16) * 32], 16, 0, 0);
      }
#pragma unroll
      for (int c = 0; c < 2; ++c) {  // B tile: 2 calls/wave/kstep (128 rows)
        int row = w * 32 + c * 16 + lrow;
        int g = lseg ^ ((row >> 2) & 3);
        const unsigned short* gp = Bt + (size_t)(bn + row) * K + kc + g * 8;
        __builtin_amdgcn_global_load_lds((const GLB void*)gp,
                                         (LDS void*)&Bs[ks][(w * 32 + c * 16) * 32], 16, 0, 0);
      }
    }
    __syncthreads();  // ONE drain per volley
#pragma unroll
    for (int ks = 0; ks < 4; ++ks) {
      const int ra = w * 16 + l16;
      short8 afr = *(const short8*)&As[ks][ra * 32 + ((quad ^ ((ra >> 2) & 3)) << 3)];
#pragma unroll
      for (int nt = 0; nt < 8; ++nt) {
        int rb = nt * 16 + l16;
        short8 bfr = *(const short8*)&Bs[ks][rb * 32 + ((quad ^ ((rb >> 2) & 3)) << 3)];
        acc[nt] = __builtin_amdgcn_mfma_f32_16x16x32_bf16(afr, bfr, acc[nt], 0, 0, 0);
      }
    }
  }
  const int h0 = blockIdx.y * 2;
  float vs[2][4] = {};
  float vd[2][4] = {};
#pragma unroll
  for (int nt = 0; nt < 8; ++nt) {
    const int h = nt >> 2;
    const float asv = a_s[(h0 + h) * 64 + (nt & 3) * 16 + l16];
    const float adv = a_d[(h0 + h) * 64 + (nt & 3) * 16 + l16];
#pragma unroll
    for (int reg = 0; reg < 4; ++reg) {
      unsigned short c = f2bf(acc[nt][reg]);
      int r = bm + w * 16 + quad * 4 + reg;
      if (r < NN) Cb[(size_t)r * 256 + bn + nt * 16 + l16] = c;
      float hv = bf2f(c);
      vs[h][reg] += hv * asv;
      vd[h][reg] += hv * adv;
    }
  }
#pragma unroll
  for (int off = 1; off < 16; off <<= 1) {
#pragma unroll
    for (int h = 0; h < 2; ++h)
#pragma unroll
      for (int reg = 0; reg < 4; ++reg) {
        vs[h][reg] += __shfl_xor(vs[h][reg], off, 64);
        vd[h][reg] += __shfl_xor(vd[h][reg], off, 64);
      }
  }
  if (l16 == 0) {
#pragma unroll
    for (int reg = 0; reg < 4; ++reg) {
      int r = bm + w * 16 + quad * 4 + reg;
      if (r < NN) {
#pragma unroll
        for (int h = 0; h < 2; ++h) {
          als[(size_t)r * 4 + h0 + h] = vs[h][reg];
          ald[(size_t)r * 4 + h0 + h] = vd[h][reg];
          selfex[(size_t)r * 4 + h0 + h] = __expf(leaky(vs[h][reg] + vd[h][reg]));
        }
      }
    }
  }
}

// ==== layer-2 GEMM: BM=64/BN=64, volley-staged, H=1 epilogue ================
__global__ __launch_bounds__(256) void gemm64v_k(const unsigned short* __restrict__ A,
                                                 const unsigned short* __restrict__ Bt,
                                                 unsigned short* __restrict__ Cb,
                                                 int K,
                                                 const float* __restrict__ a_s,
                                                 const float* __restrict__ a_d,
                                                 float* __restrict__ als,
                                                 float* __restrict__ ald,
                                                 float* __restrict__ selfex) {
  __shared__ __align__(16) unsigned short As[4][64 * 32];  // 16 KB
  __shared__ __align__(16) unsigned short Bs[4][64 * 32];  // 16 KB
  const int tid = threadIdx.x;
  const int lane = tid & 63;
  const int w = tid >> 6;
  const int bm = blockIdx.x * 64;
  const int quad = lane >> 4;
  const int l16 = lane & 15;
  const int lrow = lane >> 2;
  const int lseg = lane & 3;
  f32x4 acc[4] = {};

  for (int kv = 0; kv < K; kv += 128) {
    if (kv) __syncthreads();
#pragma unroll
    for (int ks = 0; ks < 4; ++ks) {
      const int kc = kv + ks * 32;
      {  // A tile
        int row = w * 16 + lrow;
        int g = lseg ^ ((row >> 2) & 3);
        int sr = bm + row; if (sr >= NN) sr = NN - 1;
        const unsigned short* gp = A + (size_t)sr * K + kc + g * 8;
        __builtin_amdgcn_global_load_lds((const GLB void*)gp,
                                         (LDS void*)&As[ks][(w * 16) * 32], 16, 0, 0);
      }
      {  // B tile (64 rows exact)
        int row = w * 16 + lrow;
        int g = lseg ^ ((row >> 2) & 3);
        const unsigned short* gp = Bt + (size_t)row * K + kc + g * 8;
        __builtin_amdgcn_global_load_lds((const GLB void*)gp,
                                         (LDS void*)&Bs[ks][(w * 16) * 32], 16, 0, 0);
      }
    }
    __syncthreads();
#pragma unroll
    for (int ks = 0; ks < 4; ++ks) {
      const int ra = w * 16 + l16;
      short8 afr = *(const short8*)&As[ks][ra * 32 + ((quad ^ ((ra >> 2) & 3)) << 3)];
#pragma unroll
      for (int nt = 0; nt < 4; ++nt) {
        int rb = nt * 16 + l16;
        short8 bfr = *(const short8*)&Bs[ks][rb * 32 + ((quad ^ ((rb >> 2) & 3)) << 3)];
        acc[nt] = __builtin_amdgcn_mfma_f32_16x16x32_bf16(afr, bfr, acc[nt], 0, 0, 0);
      }
    }
  }
  float vs[4] = {};
  float vd[4] = {};
#pragma unroll
  for (int nt = 0; nt < 4; ++nt) {
    const float asv = a_s[nt * 16 + l16];
    const float adv = a_d[nt * 16 + l16];
#pragma unroll
    for (int reg = 0; reg < 4; ++reg) {
      unsigned short c = f2bf(acc[nt][reg]);
      int r = bm + w * 16 + quad * 4 + reg;
      if (r < NN) Cb[(size_t)r * 64 + nt * 16 + l16] = c;
      float hv = bf2f(c);
      vs[reg] += hv * asv;
      vd[reg] += hv * adv;
    }
  }
#pragma unroll
  for (int off = 1; off < 16; off <<= 1) {
#pragma unroll
    for (int reg = 0; reg < 4; ++reg) {
      vs[reg] += __shfl_xor(vs[reg], off, 64);
      vd[reg] += __shfl_xor(vd[reg], off, 64);
    }
  }
  if (l16 == 0) {
#pragma unroll
    for (int reg = 0; reg < 4; ++reg) {
      int r = bm + w * 16 + quad * 4 + reg;
      if (r < NN) {
        als[r] = vs[reg];
        ald[r] = vd[reg];
        selfex[r] = __expf(leaky(vs[reg] + vd[reg]));
      }
    }
  }
}

// ====== gather-aggregate H=4 (round-23): XCD channel-slicing ================
// Block b: slice = b%8 (32 channels), dst-group = b/8. Workgroups round-robin
// over the 8 XCDs, so XCD k sees ONLY slice k -> its feature working set is
// NN*32ch*2B = 3.2 MB < 4 MB L2 -> random feature reads become L2 hits after
// the compulsory fill. HBM fetch should drop 211 MB -> ~90 MB (csr lines x8 +
// table once). Wave layout: 16 slots x 4 lanes x 8ch; 16 independent edge
// chains/wave (2x round-20's ILP at LOWER VGPR, avoiding r9's occupancy trap).
// Costs 2x exp recompute (VALU headroom exists) and 8x shfl-reduce spread
// over 8x the waves. Degrades gracefully to ~66us if the %8 mapping is wrong.
__global__ __launch_bounds__(256) void aggr4s_k(const int* __restrict__ deg,
                                                const int* __restrict__ csr_src,
                                                const float* __restrict__ als,
                                                const float* __restrict__ ald,
                                                const float* __restrict__ selfex,
                                                const uint4* __restrict__ hb4,
                                                const float* __restrict__ bias,
                                                uint4* __restrict__ out4) {
  const int b = blockIdx.x;
  const int slice = b & 7;
  const int dst = (b >> 3) * 4 + (threadIdx.x >> 6);
  const int lane = threadIdx.x & 63;
  const int slot = lane >> 2;     // 0..15
  const int l4 = lane & 3;
  const int head = slice >> 1;
  const int rs = dst << 6;        // fixed-stride CSR
  int dg = deg[dst]; dg = dg < 64 ? dg : 64;
  const float aldv = ald[dst * 4 + head];
  const uint4* hp = hb4 + slice * 4 + l4;  // + s*32 per node row (512B)

  float acc[8] = {};
  float dsum = 0.f;
  if (slot == 0) {  // self-loop (4 lanes)
    float a = selfex[dst * 4 + head];
    dsum = a;
    accum8(a, hp[(size_t)dst * 32], acc);
  }
  for (int j = slot; j < dg; j += 16) {  // 16 edges in flight per wave
    int s = csr_src[rs + j];
    float e = als[s * 4 + head];
    uint4 v = hp[(size_t)s * 32];
    float a = __expf(leaky(e + aldv));
    dsum += a;
    accum8(a, v, acc);
  }
  // reduce across the 16 slots (lane bits 2..5), keeping l4 lanes distinct
#pragma unroll
  for (int k = 0; k < 8; ++k) {
    acc[k] += __shfl_xor(acc[k], 4, 64);
    acc[k] += __shfl_xor(acc[k], 8, 64);
    acc[k] += __shfl_xor(acc[k], 16, 64);
    acc[k] += __shfl_xor(acc[k], 32, 64);
  }
  dsum += __shfl_xor(dsum, 4, 64);
  dsum += __shfl_xor(dsum, 8, 64);
  dsum += __shfl_xor(dsum, 16, 64);
  dsum += __shfl_xor(dsum, 32, 64);
  if (slot == 0) {  // 4 lanes write the dst's 32-ch slice (relu + bias)
    const float inv = 1.f / (dsum + 1e-16f);
    const float* bz = bias + slice * 32 + l4 * 8;
    uint4 o;
    float c0, c1;
    c0 = fmaxf(acc[0] * inv + bz[0], 0.f); c1 = fmaxf(acc[1] * inv + bz[1], 0.f);
    o.x = ((unsigned int)f2bf(c1) << 16) | f2bf(c0);
    c0 = fmaxf(acc[2] * inv + bz[2], 0.f); c1 = fmaxf(acc[3] * inv + bz[3], 0.f);
    o.y = ((unsigned int)f2bf(c1) << 16) | f2bf(c0);
    c0 = fmaxf(acc[4] * inv + bz[4], 0.f); c1 = fmaxf(acc[5] * inv + bz[5], 0.f);
    o.z = ((unsigned int)f2bf(c1) << 16) | f2bf(c0);
    c0 = fmaxf(acc[6] * inv + bz[6], 0.f); c1 = fmaxf(acc[7] * inv + bz[7], 0.f);
    o.w = ((unsigned int)f2bf(c1) << 16) | f2bf(c0);
    out4[(size_t)dst * 32 + slice * 4 + l4] = o;
  }
}

// ====== gather-aggregate H=1 (round-18 form): 2 edges/slot per iteration ====
__global__ __launch_bounds__(256) void aggr1c_k(const int* __restrict__ deg,
                                                const int* __restrict__ csr_src,
                                                const float* __restrict__ als,
                                                const float* __restrict__ ald,
                                                const float* __restrict__ selfex,
                                                const uint4* __restrict__ hb4,
                                                const float* __restrict__ bias,
                                                float* __restrict__ out) {
  const int dst = blockIdx.x * 4 + (threadIdx.x >> 6);
  const int lane = threadIdx.x & 63;
  const int slot = lane >> 3;
  const int c8 = lane & 7;
  const int rs = dst << 6;                 // fixed-stride CSR
  int dg = deg[dst]; dg = dg < 64 ? dg : 64;
  const float aldv = ald[dst];

  float acc[8] = {};
  float dsum = 0.f;
  if (slot == 0) {
    float a = selfex[dst];
    dsum += a;
    uint4 v = hb4[(size_t)dst * 8 + c8];
    accum8(a, v, acc);
  }
  int j = slot;
  for (; j + 8 < dg; j += 16) {  // 2 edges/slot in flight
    int s0 = csr_src[rs + j];
    int s1 = csr_src[rs + j + 8];
    float e0 = als[s0];
    float e1 = als[s1];
    uint4 v0 = hb4[(size_t)s0 * 8 + c8];
    uint4 v1 = hb4[(size_t)s1 * 8 + c8];
    float a0 = __expf(leaky(e0 + aldv));
    float a1 = __expf(leaky(e1 + aldv));
    dsum += a0 + a1;
    accum8(a0, v0, acc);
    accum8(a1, v1, acc);
  }
  for (; j < dg; j += 8) {
    int s = csr_src[rs + j];
    float e = als[s];
    uint4 v = hb4[(size_t)s * 8 + c8];
    float a = __expf(leaky(e + aldv));
    dsum += a;
    accum8(a, v, acc);
  }
#pragma unroll
  for (int k = 0; k < 8; ++k) {
    acc[k] += __shfl_xor(acc[k], 8, 64);
    acc[k] += __shfl_xor(acc[k], 16, 64);
    acc[k] += __shfl_xor(acc[k], 32, 64);
  }
  dsum += __shfl_xor(dsum, 8, 64);
  dsum += __shfl_xor(dsum, 16, 64);
  dsum += __shfl_xor(dsum, 32, 64);
  if (slot == 0) {  // no relu on layer 2; fp32 out
    const float inv = 1.f / (dsum + 1e-16f);
    const float4 bz0 = *(const float4*)(bias + c8 * 8);
    const float4 bz1 = *(const float4*)(bias + c8 * 8 + 4);
    float4 o0 = make_float4(acc[0] * inv + bz0.x, acc[1] * inv + bz0.y,
                            acc[2] * inv + bz0.z, acc[3] * inv + bz0.w);
    float4 o1 = make_float4(acc[4] * inv + bz1.x, acc[5] * inv + bz1.y,
                            acc[6] * inv + bz1.z, acc[7] * inv + bz1.w);
    *(float4*)(out + (size_t)dst * 64 + c8 * 8) = o0;
    *(float4*)(out + (size_t)dst * 64 + c8 * 8 + 4) = o1;
  }
}

// ---- fused prep (round-22): histscat (leading blocks) + x cast + W^T + g ---
#define HS_BLK 782          // ceil(EE / 1024)
__global__ __launch_bounds__(256) void prep_k(const int* __restrict__ ei,
                                              int* __restrict__ deg,
                                              int* __restrict__ csr_src,
                                              const float2* __restrict__ x2,
                                              unsigned int* __restrict__ xb_u,
                                              const float* __restrict__ W0,
                                              unsigned short* __restrict__ W0t,
                                              const float* __restrict__ W1,
                                              unsigned short* __restrict__ W1t,
                                              const float* __restrict__ W2,
                                              unsigned short* __restrict__ W2t,
                                              float* __restrict__ g) {
  int bid = blockIdx.x;
  int tid = threadIdx.x;
  if (bid < HS_BLK) {  // fused hist+scatter, 4 edges/thread
    const int base = bid * 1024 + tid;
    int ss[4], dd[4], jj[4];
#pragma unroll
    for (int k = 0; k < 4; ++k) {
      int i = base + k * 256;
      bool m = i < EE;
      ss[k] = m ? ei[i] : 0;
      dd[k] = m ? ei[EE + i] : 0;
      jj[k] = 64;
      if (m) jj[k] = atomicAdd(&deg[dd[k]], 1);
    }
#pragma unroll
    for (int k = 0; k < 4; ++k)
      if (jj[k] < 64) csr_src[(dd[k] << 6) + jj[k]] = ss[k];
    return;
  }
  bid -= HS_BLK;
  if (bid < 12500) {  // castx: NN*128/2 = 3.2M uints
    int i = bid * 256 + tid;
    float2 v = x2[i];
    xb_u[i] = ((unsigned int)f2bf(v.y) << 16) | f2bf(v.x);
    return;
  }
  if (bid < 12948) {  // weight transposes (448 blocks = 114688 threads exact)
    int r = (bid - 12500) * 256 + tid;
    if (r < 32768) {            // W0t[256][128] <- W0[128][256]
      int n = r >> 7, k = r & 127;
      W0t[n * 128 + k] = f2bf(W0[k * 256 + n]);
    } else if (r < 98304) {     // W1t[256][256] <- W1[256][256]
      int rr = r - 32768;
      int n = rr >> 8, k = rr & 255;
      W1t[n * 256 + k] = f2bf(W1[k * 256 + n]);
    } else {                    // W2t[64][256] <- W2[256][64]
      int rr = r - 98304;
      int n = rr >> 8, k = rr & 255;
      W2t[n * 256 + k] = f2bf(W2[k * 64 + n]);
    }
    return;
  }
  if (tid < 68) g[tid] = 0.f;  // g sums + counter
}

// ---- colsum + fused head: last block computes the final [1,64] output ------
__global__ __launch_bounds__(256) void colsum_head_k(const float* __restrict__ h2,
                                                     float* __restrict__ g,
                                                     unsigned int* __restrict__ cnt,
                                                     const float* __restrict__ hw,
                                                     const float* __restrict__ hb,
                                                     float* __restrict__ out) {
  __shared__ float s[256];
  __shared__ float sg[64];
  __shared__ unsigned int sdone;
  int tid = threadIdx.x;
  int c = tid & 63, rg = tid >> 6;
  float acc = 0.f;
  for (int n = blockIdx.x * 4 + rg; n < NN; n += gridDim.x * 4)
    acc += h2[n * 64 + c];
  s[tid] = acc;
  __syncthreads();
  if (tid < 64) atomicAdd(&g[c], s[c] + s[64 + c] + s[128 + c] + s[192 + c]);
  __threadfence();
  __syncthreads();
  if (tid == 0) sdone = atomicAdd(cnt, 1);
  __syncthreads();
  if (sdone != gridDim.x - 1) return;
  if (tid < 64) sg[tid] = atomicAdd(&g[tid], 0.f);  // coherent read
  __syncthreads();
  if (tid < 64) {
    const float invN = 1.0f / (float)NN;
    float a2 = hb[tid];
#pragma unroll 8
    for (int cc = 0; cc < 64; ++cc) a2 += sg[cc] * invN * hw[cc * 64 + tid];
    out[tid] = a2;
  }
}

extern "C" void kernel_launch(void* const* d_in, const int* in_sizes, int n_in,
                              void* d_out, int out_size, void* d_ws, size_t ws_size,
                              hipStream_t stream) {
  const float* x   = (const float*)d_in[0];
  const int*   ei  = (const int*)d_in[1];
  const float* W0  = (const float*)d_in[2];
  const float* a0s = (const float*)d_in[3];
  const float* a0d = (const float*)d_in[4];
  const float* b0  = (const float*)d_in[5];
  const float* W1  = (const float*)d_in[6];
  const float* a1s = (const float*)d_in[7];
  const float* a1d = (const float*)d_in[8];
  const float* b1  = (const float*)d_in[9];
  const float* W2  = (const float*)d_in[10];
  const float* a2s = (const float*)d_in[11];
  const float* a2d = (const float*)d_in[12];
  const float* b2  = (const float*)d_in[13];
  const float* hw  = (const float*)d_in[14];
  const float* hb  = (const float*)d_in[15];
  float* out = (float*)d_out;

  char* w = (char*)d_ws;
  unsigned short* xb   = (unsigned short*)w; w += (size_t)NN * 128 * 2;
  unsigned short* bufG = (unsigned short*)w; w += (size_t)NN * 256 * 2;
  unsigned short* bufA = (unsigned short*)w; w += (size_t)NN * 256 * 2;
  float* bufF = (float*)w;                   w += (size_t)NN * 64 * 4;
  unsigned short* W0t = (unsigned short*)w;  w += 256 * 128 * 2;
  unsigned short* W1t = (unsigned short*)w;  w += 256 * 256 * 2;
  unsigned short* W2t = (unsigned short*)w;  w += 64 * 256 * 2;
  float* als  = (float*)w;    w += (size_t)NN * 4 * 4;
  float* ald  = (float*)w;    w += (size_t)NN * 4 * 4;
  float* sfx  = (float*)w;    w += (size_t)NN * 4 * 4;
  int* deg     = (int*)w;     w += (size_t)NN * 4;
  int* csr_src = (int*)w;     w += (size_t)NN * 64 * 4;   // 12.8 MB fixed-stride
  float* g    = (float*)w;    w += 256;           // g[0..63] sums; cnt at g+64

  // deg must be zero before prep's histscat blocks (memset is capture-safe)
  hipMemsetAsync(deg, 0, (size_t)NN * 4, stream);

  // ---- fused prep: histscat || castx || transposes || g-zero ----
  prep_k<<<HS_BLK + 12948 + 1, 256, 0, stream>>>(ei, deg, csr_src,
                                                 (const float2*)x, (unsigned int*)xb,
                                                 W0, W0t, W1, W1t, W2, W2t, g);

  const int G64 = (NN + 63) / 64;    // 782 row-blocks (BM=64)
  const int GA = NN / 4;             // 12500 exact
  const int GS = GA * 8;             // 100000: (dst-group, slice) pairs

  // layers 0 and 1 (H=4); slice-partitioned aggregates
  gemm128_k<0><<<dim3(G64, 2), 256, 0, stream>>>(xb, W0t, bufG, 128, a0s, a0d, als, ald, sfx);
  aggr4s_k<<<GS, 256, 0, stream>>>(deg, csr_src, als, ald, sfx,
                                   (const uint4*)bufG, b0, (uint4*)bufA);
  gemm128_k<1><<<dim3(G64, 2), 256, 0, stream>>>(bufA, W1t, bufG, 256, a1s, a1d, als, ald, sfx);
  aggr4s_k<<<GS, 256, 0, stream>>>(deg, csr_src, als, ald, sfx,
                                   (const uint4*)bufG, b1, (uint4*)bufA);

  // layer 2 (H=1)
  gemm64v_k<<<G64, 256, 0, stream>>>(bufA, W2t, bufG, 256, a2s, a2d, als, ald, sfx);
  aggr1c_k<<<GA, 256, 0, stream>>>(deg, csr_src, als, ald, sfx,
                                   (const uint4*)bufG, b2, bufF);

  // ---- mean + head (g zeroed by prep_k) ----
  colsum_head_k<<<256, 256, 0, stream>>>(bufF, g, (unsigned int*)(g + 64), hw, hb, out);
}

// Round 12
// 381.503 us; speedup vs baseline: 1.4971x; 1.4971x over previous
//
#include <hip/hip_runtime.h>
#include <hip/hip_bf16.h>
#include <cstddef>

#define NN 50000
#define EE 800000

typedef __attribute__((ext_vector_type(8))) short short8;
typedef __attribute__((ext_vector_type(4))) float f32x4;

#define GLB __attribute__((address_space(1)))
#define LDS __attribute__((address_space(3)))

__device__ __forceinline__ float leaky(float x) { return x >= 0.f ? x : 0.2f * x; }
__device__ __forceinline__ float bf2f(unsigned short u) {
  return __uint_as_float(((unsigned int)u) << 16);
}
__device__ __forceinline__ float bflo(unsigned int v) { return __uint_as_float(v << 16); }
__device__ __forceinline__ float bfhi(unsigned int v) { return __uint_as_float(v & 0xFFFF0000u); }
__device__ __forceinline__ unsigned short f2bf(float f) {
  __hip_bfloat16 b = __float2bfloat16(f);
  return __builtin_bit_cast(unsigned short, b);
}
__device__ __forceinline__ void accum8(float a, uint4 v, float* acc) {
  acc[0] += a * bflo(v.x); acc[1] += a * bfhi(v.x);
  acc[2] += a * bflo(v.y); acc[3] += a * bfhi(v.y);
  acc[4] += a * bflo(v.z); acc[5] += a * bfhi(v.z);
  acc[6] += a * bflo(v.w); acc[7] += a * bfhi(v.w);
}

// ==== bf16 MFMA GEMM, BM=64/BN=128, VOLLEY-staged (round-17) ================
template <int LAYER>
__global__ __launch_bounds__(256) void gemm128_k(const unsigned short* __restrict__ A,
                                                 const unsigned short* __restrict__ Bt,
                                                 unsigned short* __restrict__ Cb,
                                                 int K,
                                                 const float* __restrict__ a_s,
                                                 const float* __restrict__ a_d,
                                                 float* __restrict__ als,
                                                 float* __restrict__ ald,
                                                 float* __restrict__ selfex) {
  __shared__ __align__(16) unsigned short As[4][64 * 32];    // 16 KB
  __shared__ __align__(16) unsigned short Bs[4][128 * 32];   // 32 KB
  const int tid = threadIdx.x;
  const int lane = tid & 63;
  const int w = tid >> 6;
  const int bm = blockIdx.x * 64;
  const int bn = blockIdx.y * 128;
  const int quad = lane >> 4;
  const int l16 = lane & 15;
  const int lrow = lane >> 2;   // 0..15 within a staging call
  const int lseg = lane & 3;
  f32x4 acc[8] = {};

  for (int kv = 0; kv < K; kv += 128) {
    if (kv) __syncthreads();  // protect LDS reuse after previous compute
#pragma unroll
    for (int ks = 0; ks < 4; ++ks) {
      const int kc = kv + ks * 32;
      {  // A tile: 1 call/wave/kstep (16 rows, row = 64B = 4 lanes x 16B)
        int row = w * 16 + lrow;
        int g = lseg ^ ((row >> 2) & 3);
        int sr = bm + row; if (sr >= NN) sr = NN - 1;
        const unsigned short* gp = A + (size_t)sr * K + kc + g * 8;
        __builtin_amdgcn_global_load_lds((const GLB void*)gp,
                                         (LDS void*)&As[ks][(w * 16) * 32], 16, 0, 0);
      }
#pragma unroll
      for (int c = 0; c < 2; ++c) {  // B tile: 2 calls/wave/kstep (128 rows)
        int row = w * 32 + c * 16 + lrow;
        int g = lseg ^ ((row >> 2) & 3);
        const unsigned short* gp = Bt + (size_t)(bn + row) * K + kc + g * 8;
        __builtin_amdgcn_global_load_lds((const GLB void*)gp,
                                         (LDS void*)&Bs[ks][(w * 32 + c * 16) * 32], 16, 0, 0);
      }
    }
    __syncthreads();  // ONE drain per volley
#pragma unroll
    for (int ks = 0; ks < 4; ++ks) {
      const int ra = w * 16 + l16;
      short8 afr = *(const short8*)&As[ks][ra * 32 + ((quad ^ ((ra >> 2) & 3)) << 3)];
#pragma unroll
      for (int nt = 0; nt < 8; ++nt) {
        int rb = nt * 16 + l16;
        short8 bfr = *(const short8*)&Bs[ks][rb * 32 + ((quad ^ ((rb >> 2) & 3)) << 3)];
        acc[nt] = __builtin_amdgcn_mfma_f32_16x16x32_bf16(afr, bfr, acc[nt], 0, 0, 0);
      }
    }
  }
  const int h0 = blockIdx.y * 2;
  float vs[2][4] = {};
  float vd[2][4] = {};
#pragma unroll
  for (int nt = 0; nt < 8; ++nt) {
    const int h = nt >> 2;
    const float asv = a_s[(h0 + h) * 64 + (nt & 3) * 16 + l16];
    const float adv = a_d[(h0 + h) * 64 + (nt & 3) * 16 + l16];
#pragma unroll
    for (int reg = 0; reg < 4; ++reg) {
      unsigned short c = f2bf(acc[nt][reg]);
      int r = bm + w * 16 + quad * 4 + reg;
      if (r < NN) Cb[(size_t)r * 256 + bn + nt * 16 + l16] = c;
      float hv = bf2f(c);
      vs[h][reg] += hv * asv;
      vd[h][reg] += hv * adv;
    }
  }
#pragma unroll
  for (int off = 1; off < 16; off <<= 1) {
#pragma unroll
    for (int h = 0; h < 2; ++h)
#pragma unroll
      for (int reg = 0; reg < 4; ++reg) {
        vs[h][reg] += __shfl_xor(vs[h][reg], off, 64);
        vd[h][reg] += __shfl_xor(vd[h][reg], off, 64);
      }
  }
  if (l16 == 0) {
#pragma unroll
    for (int reg = 0; reg < 4; ++reg) {
      int r = bm + w * 16 + quad * 4 + reg;
      if (r < NN) {
#pragma unroll
        for (int h = 0; h < 2; ++h) {
          als[(size_t)r * 4 + h0 + h] = vs[h][reg];
          ald[(size_t)r * 4 + h0 + h] = vd[h][reg];
          selfex[(size_t)r * 4 + h0 + h] = __expf(leaky(vs[h][reg] + vd[h][reg]));
        }
      }
    }
  }
}

// ==== layer-2 GEMM: BM=64/BN=64, volley-staged, H=1 epilogue ================
__global__ __launch_bounds__(256) void gemm64v_k(const unsigned short* __restrict__ A,
                                                 const unsigned short* __restrict__ Bt,
                                                 unsigned short* __restrict__ Cb,
                                                 int K,
                                                 const float* __restrict__ a_s,
                                                 const float* __restrict__ a_d,
                                                 float* __restrict__ als,
                                                 float* __restrict__ ald,
                                                 float* __restrict__ selfex) {
  __shared__ __align__(16) unsigned short As[4][64 * 32];  // 16 KB
  __shared__ __align__(16) unsigned short Bs[4][64 * 32];  // 16 KB
  const int tid = threadIdx.x;
  const int lane = tid & 63;
  const int w = tid >> 6;
  const int bm = blockIdx.x * 64;
  const int quad = lane >> 4;
  const int l16 = lane & 15;
  const int lrow = lane >> 2;
  const int lseg = lane & 3;
  f32x4 acc[4] = {};

  for (int kv = 0; kv < K; kv += 128) {
    if (kv) __syncthreads();
#pragma unroll
    for (int ks = 0; ks < 4; ++ks) {
      const int kc = kv + ks * 32;
      {  // A tile
        int row = w * 16 + lrow;
        int g = lseg ^ ((row >> 2) & 3);
        int sr = bm + row; if (sr >= NN) sr = NN - 1;
        const unsigned short* gp = A + (size_t)sr * K + kc + g * 8;
        __builtin_amdgcn_global_load_lds((const GLB void*)gp,
                                         (LDS void*)&As[ks][(w * 16) * 32], 16, 0, 0);
      }
      {  // B tile (64 rows exact)
        int row = w * 16 + lrow;
        int g = lseg ^ ((row >> 2) & 3);
        const unsigned short* gp = Bt + (size_t)row * K + kc + g * 8;
        __builtin_amdgcn_global_load_lds((const GLB void*)gp,
                                         (LDS void*)&Bs[ks][(w * 16) * 32], 16, 0, 0);
      }
    }
    __syncthreads();
#pragma unroll
    for (int ks = 0; ks < 4; ++ks) {
      const int ra = w * 16 + l16;
      short8 afr = *(const short8*)&As[ks][ra * 32 + ((quad ^ ((ra >> 2) & 3)) << 3)];
#pragma unroll
      for (int nt = 0; nt < 4; ++nt) {
        int rb = nt * 16 + l16;
        short8 bfr = *(const short8*)&Bs[ks][rb * 32 + ((quad ^ ((rb >> 2) & 3)) << 3)];
        acc[nt] = __builtin_amdgcn_mfma_f32_16x16x32_bf16(afr, bfr, acc[nt], 0, 0, 0);
      }
    }
  }
  float vs[4] = {};
  float vd[4] = {};
#pragma unroll
  for (int nt = 0; nt < 4; ++nt) {
    const float asv = a_s[nt * 16 + l16];
    const float adv = a_d[nt * 16 + l16];
#pragma unroll
    for (int reg = 0; reg < 4; ++reg) {
      unsigned short c = f2bf(acc[nt][reg]);
      int r = bm + w * 16 + quad * 4 + reg;
      if (r < NN) Cb[(size_t)r * 64 + nt * 16 + l16] = c;
      float hv = bf2f(c);
      vs[reg] += hv * asv;
      vd[reg] += hv * adv;
    }
  }
#pragma unroll
  for (int off = 1; off < 16; off <<= 1) {
#pragma unroll
    for (int reg = 0; reg < 4; ++reg) {
      vs[reg] += __shfl_xor(vs[reg], off, 64);
      vd[reg] += __shfl_xor(vd[reg], off, 64);
    }
  }
  if (l16 == 0) {
#pragma unroll
    for (int reg = 0; reg < 4; ++reg) {
      int r = bm + w * 16 + quad * 4 + reg;
      if (r < NN) {
        als[r] = vs[reg];
        ald[r] = vd[reg];
        selfex[r] = __expf(leaky(vs[reg] + vd[reg]));
      }
    }
  }
}

// ====== gather-aggregate H=4 (round-20 form: measured 66.5us floor) =========
// Floor arithmetic: ~235 MB compulsory per-XCD traffic at 3.6-3.9 TB/s
// fabric service = 60-65us. Three ILP-deepening attempts (r1 pipeline, r9
// volley, r11 XCD-slicing) all lost more occupancy/VALU than gained. FINAL.
__global__ __launch_bounds__(256) void aggr4c_k(const int* __restrict__ deg,
                                                const int* __restrict__ csr_src,
                                                const float* __restrict__ als,
                                                const float* __restrict__ ald,
                                                const float* __restrict__ selfex,
                                                const uint4* __restrict__ hb4,
                                                const float* __restrict__ bias,
                                                uint4* __restrict__ out4) {
  const int dst = blockIdx.x * 4 + (threadIdx.x >> 6);
  const int lane = threadIdx.x & 63;
  const int slot = lane >> 4;
  const int l16 = lane & 15;
  const int head = l16 >> 2;
  const int rs = dst << 6;                 // fixed-stride CSR
  int dg = deg[dst]; dg = dg < 64 ? dg : 64;
  const float aldv = ald[dst * 4 + head];

  float acc[16] = {};
  float dsum = 0.f;
  if (slot == 0) {  // self-loop (unnormalized)
    float a = selfex[dst * 4 + head];
    dsum += a;
    uint4 v0 = hb4[(size_t)dst * 32 + l16 * 2];
    uint4 v1 = hb4[(size_t)dst * 32 + l16 * 2 + 1];
    accum8(a, v0, acc);
    accum8(a, v1, acc + 8);
  }
  int j = slot;
  for (; j + 4 < dg; j += 8) {
    int s0 = csr_src[rs + j];
    int s1 = csr_src[rs + j + 4];
    float e0 = als[s0 * 4 + head];
    float e1 = als[s1 * 4 + head];
    uint4 va0 = hb4[(size_t)s0 * 32 + l16 * 2];
    uint4 vb0 = hb4[(size_t)s0 * 32 + l16 * 2 + 1];
    uint4 va1 = hb4[(size_t)s1 * 32 + l16 * 2];
    uint4 vb1 = hb4[(size_t)s1 * 32 + l16 * 2 + 1];
    float a0 = __expf(leaky(e0 + aldv));
    float a1 = __expf(leaky(e1 + aldv));
    dsum += a0 + a1;
    accum8(a0, va0, acc);
    accum8(a0, vb0, acc + 8);
    accum8(a1, va1, acc);
    accum8(a1, vb1, acc + 8);
  }
  for (; j < dg; j += 4) {
    int s0 = csr_src[rs + j];
    float e0 = als[s0 * 4 + head];
    uint4 va0 = hb4[(size_t)s0 * 32 + l16 * 2];
    uint4 vb0 = hb4[(size_t)s0 * 32 + l16 * 2 + 1];
    float a0 = __expf(leaky(e0 + aldv));
    dsum += a0;
    accum8(a0, va0, acc);
    accum8(a0, vb0, acc + 8);
  }
#pragma unroll
  for (int k = 0; k < 16; ++k) {
    acc[k] += __shfl_xor(acc[k], 16, 64);
    acc[k] += __shfl_xor(acc[k], 32, 64);
  }
  dsum += __shfl_xor(dsum, 16, 64);
  dsum += __shfl_xor(dsum, 32, 64);
  if (slot == 0) {  // channels [l16*16, l16*16+16), relu (both H=4 layers)
    const float inv = 1.f / (dsum + 1e-16f);
    const float* bz = bias + l16 * 16;
    uint4 o0, o1;
    float c0, c1;
    c0 = fmaxf(acc[0] * inv + bz[0], 0.f);   c1 = fmaxf(acc[1] * inv + bz[1], 0.f);
    o0.x = ((unsigned int)f2bf(c1) << 16) | f2bf(c0);
    c0 = fmaxf(acc[2] * inv + bz[2], 0.f);   c1 = fmaxf(acc[3] * inv + bz[3], 0.f);
    o0.y = ((unsigned int)f2bf(c1) << 16) | f2bf(c0);
    c0 = fmaxf(acc[4] * inv + bz[4], 0.f);   c1 = fmaxf(acc[5] * inv + bz[5], 0.f);
    o0.z = ((unsigned int)f2bf(c1) << 16) | f2bf(c0);
    c0 = fmaxf(acc[6] * inv + bz[6], 0.f);   c1 = fmaxf(acc[7] * inv + bz[7], 0.f);
    o0.w = ((unsigned int)f2bf(c1) << 16) | f2bf(c0);
    c0 = fmaxf(acc[8] * inv + bz[8], 0.f);   c1 = fmaxf(acc[9] * inv + bz[9], 0.f);
    o1.x = ((unsigned int)f2bf(c1) << 16) | f2bf(c0);
    c0 = fmaxf(acc[10] * inv + bz[10], 0.f); c1 = fmaxf(acc[11] * inv + bz[11], 0.f);
    o1.y = ((unsigned int)f2bf(c1) << 16) | f2bf(c0);
    c0 = fmaxf(acc[12] * inv + bz[12], 0.f); c1 = fmaxf(acc[13] * inv + bz[13], 0.f);
    o1.z = ((unsigned int)f2bf(c1) << 16) | f2bf(c0);
    c0 = fmaxf(acc[14] * inv + bz[14], 0.f); c1 = fmaxf(acc[15] * inv + bz[15], 0.f);
    o1.w = ((unsigned int)f2bf(c1) << 16) | f2bf(c0);
    out4[(size_t)dst * 32 + l16 * 2] = o0;
    out4[(size_t)dst * 32 + l16 * 2 + 1] = o1;
  }
}

// ====== gather-aggregate H=1 (round-18 form): 2 edges/slot per iteration ====
__global__ __launch_bounds__(256) void aggr1c_k(const int* __restrict__ deg,
                                                const int* __restrict__ csr_src,
                                                const float* __restrict__ als,
                                                const float* __restrict__ ald,
                                                const float* __restrict__ selfex,
                                                const uint4* __restrict__ hb4,
                                                const float* __restrict__ bias,
                                                float* __restrict__ out) {
  const int dst = blockIdx.x * 4 + (threadIdx.x >> 6);
  const int lane = threadIdx.x & 63;
  const int slot = lane >> 3;
  const int c8 = lane & 7;
  const int rs = dst << 6;                 // fixed-stride CSR
  int dg = deg[dst]; dg = dg < 64 ? dg : 64;
  const float aldv = ald[dst];

  float acc[8] = {};
  float dsum = 0.f;
  if (slot == 0) {
    float a = selfex[dst];
    dsum += a;
    uint4 v = hb4[(size_t)dst * 8 + c8];
    accum8(a, v, acc);
  }
  int j = slot;
  for (; j + 8 < dg; j += 16) {  // 2 edges/slot in flight
    int s0 = csr_src[rs + j];
    int s1 = csr_src[rs + j + 8];
    float e0 = als[s0];
    float e1 = als[s1];
    uint4 v0 = hb4[(size_t)s0 * 8 + c8];
    uint4 v1 = hb4[(size_t)s1 * 8 + c8];
    float a0 = __expf(leaky(e0 + aldv));
    float a1 = __expf(leaky(e1 + aldv));
    dsum += a0 + a1;
    accum8(a0, v0, acc);
    accum8(a1, v1, acc);
  }
  for (; j < dg; j += 8) {
    int s = csr_src[rs + j];
    float e = als[s];
    uint4 v = hb4[(size_t)s * 8 + c8];
    float a = __expf(leaky(e + aldv));
    dsum += a;
    accum8(a, v, acc);
  }
#pragma unroll
  for (int k = 0; k < 8; ++k) {
    acc[k] += __shfl_xor(acc[k], 8, 64);
    acc[k] += __shfl_xor(acc[k], 16, 64);
    acc[k] += __shfl_xor(acc[k], 32, 64);
  }
  dsum += __shfl_xor(dsum, 8, 64);
  dsum += __shfl_xor(dsum, 16, 64);
  dsum += __shfl_xor(dsum, 32, 64);
  if (slot == 0) {  // no relu on layer 2; fp32 out
    const float inv = 1.f / (dsum + 1e-16f);
    const float4 bz0 = *(const float4*)(bias + c8 * 8);
    const float4 bz1 = *(const float4*)(bias + c8 * 8 + 4);
    float4 o0 = make_float4(acc[0] * inv + bz0.x, acc[1] * inv + bz0.y,
                            acc[2] * inv + bz0.z, acc[3] * inv + bz0.w);
    float4 o1 = make_float4(acc[4] * inv + bz1.x, acc[5] * inv + bz1.y,
                            acc[6] * inv + bz1.z, acc[7] * inv + bz1.w);
    *(float4*)(out + (size_t)dst * 64 + c8 * 8) = o0;
    *(float4*)(out + (size_t)dst * 64 + c8 * 8 + 4) = o1;
  }
}

// ---- fused prep (round-22): histscat (leading blocks) + x cast + W^T + g ---
#define HS_BLK 782          // ceil(EE / 1024)
__global__ __launch_bounds__(256) void prep_k(const int* __restrict__ ei,
                                              int* __restrict__ deg,
                                              int* __restrict__ csr_src,
                                              const float2* __restrict__ x2,
                                              unsigned int* __restrict__ xb_u,
                                              const float* __restrict__ W0,
                                              unsigned short* __restrict__ W0t,
                                              const float* __restrict__ W1,
                                              unsigned short* __restrict__ W1t,
                                              const float* __restrict__ W2,
                                              unsigned short* __restrict__ W2t,
                                              float* __restrict__ g) {
  int bid = blockIdx.x;
  int tid = threadIdx.x;
  if (bid < HS_BLK) {  // fused hist+scatter, 4 edges/thread
    const int base = bid * 1024 + tid;
    int ss[4], dd[4], jj[4];
#pragma unroll
    for (int k = 0; k < 4; ++k) {
      int i = base + k * 256;
      bool m = i < EE;
      ss[k] = m ? ei[i] : 0;
      dd[k] = m ? ei[EE + i] : 0;
      jj[k] = 64;
      if (m) jj[k] = atomicAdd(&deg[dd[k]], 1);
    }
#pragma unroll
    for (int k = 0; k < 4; ++k)
      if (jj[k] < 64) csr_src[(dd[k] << 6) + jj[k]] = ss[k];
    return;
  }
  bid -= HS_BLK;
  if (bid < 12500) {  // castx: NN*128/2 = 3.2M uints
    int i = bid * 256 + tid;
    float2 v = x2[i];
    xb_u[i] = ((unsigned int)f2bf(v.y) << 16) | f2bf(v.x);
    return;
  }
  if (bid < 12948) {  // weight transposes (448 blocks = 114688 threads exact)
    int r = (bid - 12500) * 256 + tid;
    if (r < 32768) {            // W0t[256][128] <- W0[128][256]
      int n = r >> 7, k = r & 127;
      W0t[n * 128 + k] = f2bf(W0[k * 256 + n]);
    } else if (r < 98304) {     // W1t[256][256] <- W1[256][256]
      int rr = r - 32768;
      int n = rr >> 8, k = rr & 255;
      W1t[n * 256 + k] = f2bf(W1[k * 256 + n]);
    } else {                    // W2t[64][256] <- W2[256][64]
      int rr = r - 98304;
      int n = rr >> 8, k = rr & 255;
      W2t[n * 256 + k] = f2bf(W2[k * 64 + n]);
    }
    return;
  }
  if (tid < 68) g[tid] = 0.f;  // g sums + counter
}

// ---- colsum + fused head: last block computes the final [1,64] output ------
__global__ __launch_bounds__(256) void colsum_head_k(const float* __restrict__ h2,
                                                     float* __restrict__ g,
                                                     unsigned int* __restrict__ cnt,
                                                     const float* __restrict__ hw,
                                                     const float* __restrict__ hb,
                                                     float* __restrict__ out) {
  __shared__ float s[256];
  __shared__ float sg[64];
  __shared__ unsigned int sdone;
  int tid = threadIdx.x;
  int c = tid & 63, rg = tid >> 6;
  float acc = 0.f;
  for (int n = blockIdx.x * 4 + rg; n < NN; n += gridDim.x * 4)
    acc += h2[n * 64 + c];
  s[tid] = acc;
  __syncthreads();
  if (tid < 64) atomicAdd(&g[c], s[c] + s[64 + c] + s[128 + c] + s[192 + c]);
  __threadfence();
  __syncthreads();
  if (tid == 0) sdone = atomicAdd(cnt, 1);
  __syncthreads();
  if (sdone != gridDim.x - 1) return;
  if (tid < 64) sg[tid] = atomicAdd(&g[tid], 0.f);  // coherent read
  __syncthreads();
  if (tid < 64) {
    const float invN = 1.0f / (float)NN;
    float a2 = hb[tid];
#pragma unroll 8
    for (int cc = 0; cc < 64; ++cc) a2 += sg[cc] * invN * hw[cc * 64 + tid];
    out[tid] = a2;
  }
}

extern "C" void kernel_launch(void* const* d_in, const int* in_sizes, int n_in,
                              void* d_out, int out_size, void* d_ws, size_t ws_size,
                              hipStream_t stream) {
  const float* x   = (const float*)d_in[0];
  const int*   ei  = (const int*)d_in[1];
  const float* W0  = (const float*)d_in[2];
  const float* a0s = (const float*)d_in[3];
  const float* a0d = (const float*)d_in[4];
  const float* b0  = (const float*)d_in[5];
  const float* W1  = (const float*)d_in[6];
  const float* a1s = (const float*)d_in[7];
  const float* a1d = (const float*)d_in[8];
  const float* b1  = (const float*)d_in[9];
  const float* W2  = (const float*)d_in[10];
  const float* a2s = (const float*)d_in[11];
  const float* a2d = (const float*)d_in[12];
  const float* b2  = (const float*)d_in[13];
  const float* hw  = (const float*)d_in[14];
  const float* hb  = (const float*)d_in[15];
  float* out = (float*)d_out;

  char* w = (char*)d_ws;
  unsigned short* xb   = (unsigned short*)w; w += (size_t)NN * 128 * 2;
  unsigned short* bufG = (unsigned short*)w; w += (size_t)NN * 256 * 2;
  unsigned short* bufA = (unsigned short*)w; w += (size_t)NN * 256 * 2;
  float* bufF = (float*)w;                   w += (size_t)NN * 64 * 4;
  unsigned short* W0t = (unsigned short*)w;  w += 256 * 128 * 2;
  unsigned short* W1t = (unsigned short*)w;  w += 256 * 256 * 2;
  unsigned short* W2t = (unsigned short*)w;  w += 64 * 256 * 2;
  float* als  = (float*)w;    w += (size_t)NN * 4 * 4;
  float* ald  = (float*)w;    w += (size_t)NN * 4 * 4;
  float* sfx  = (float*)w;    w += (size_t)NN * 4 * 4;
  int* deg     = (int*)w;     w += (size_t)NN * 4;
  int* csr_src = (int*)w;     w += (size_t)NN * 64 * 4;   // 12.8 MB fixed-stride
  float* g    = (float*)w;    w += 256;           // g[0..63] sums; cnt at g+64

  // deg must be zero before prep's histscat blocks (memset is capture-safe)
  hipMemsetAsync(deg, 0, (size_t)NN * 4, stream);

  // ---- fused prep: histscat || castx || transposes || g-zero ----
  prep_k<<<HS_BLK + 12948 + 1, 256, 0, stream>>>(ei, deg, csr_src,
                                                 (const float2*)x, (unsigned int*)xb,
                                                 W0, W0t, W1, W1t, W2, W2t, g);

  const int G64 = (NN + 63) / 64;    // 782 row-blocks (BM=64)
  const int GA = NN / 4;             // 12500 exact

  // layers 0 and 1 (H=4)
  gemm128_k<0><<<dim3(G64, 2), 256, 0, stream>>>(xb, W0t, bufG, 128, a0s, a0d, als, ald, sfx);
  aggr4c_k<<<GA, 256, 0, stream>>>(deg, csr_src, als, ald, sfx,
                                   (const uint4*)bufG, b0, (uint4*)bufA);
  gemm128_k<1><<<dim3(G64, 2), 256, 0, stream>>>(bufA, W1t, bufG, 256, a1s, a1d, als, ald, sfx);
  aggr4c_k<<<GA, 256, 0, stream>>>(deg, csr_src, als, ald, sfx,
                                   (const uint4*)bufG, b1, (uint4*)bufA);

  // layer 2 (H=1)
  gemm64v_k<<<G64, 256, 0, stream>>>(bufA, W2t, bufG, 256, a2s, a2d, als, ald, sfx);
  aggr1c_k<<<GA, 256, 0, stream>>>(deg, csr_src, als, ald, sfx,
                                   (const uint4*)bufG, b2, bufF);

  // ---- mean + head (g zeroed by prep_k) ----
  colsum_head_k<<<256, 256, 0, stream>>>(bufF, g, (unsigned int*)(g + 64), hw, hb, out);
}